// Round 4
// baseline (120.677 us; speedup 1.0000x reference)
//
#include <hip/hip_runtime.h>

typedef __bf16 bf16x8 __attribute__((ext_vector_type(8)));
typedef float  f32x4  __attribute__((ext_vector_type(4)));

constexpr int BN  = 262144;
constexpr int DIN = 100;
constexpr int DH  = 200;
constexpr int DZ  = 20;
constexpr int KCB = 512;

// ws byte offsets (all 16B-aligned)
constexpr size_t WS_W1F  = 0;        // [16 nt][4 kk][512] bf16 = 65536 B
constexpr size_t WS_W2F  = 65536;    // [2 zt][8 kk][512] bf16 = 16384 B
constexpr size_t WS_CBF  = 81920;    // [32 ct][512] bf16 = 32768 B (k=20 slot holds ||cb||^2)
constexpr size_t WS_WMUF = 114688;   // [2 zt][512] bf16 = 2048 B
constexpr size_t WS_WLVF = 116736;   // 2048 B
constexpr size_t WS_B1P  = 118784;   // 256 f32
constexpr size_t WS_B2P  = 119808;   // 32 f32
constexpr size_t WS_BMUP = 119936;   // 32 f32
constexpr size_t WS_BLVP = 120064;   // 32 f32
constexpr size_t WS_PART = 120192;   // 2048 f32 (per-block loss partials)

// prep element counts
constexpr int PN_W1 = 32768, PN_W2 = 8192, PN_CB = 16384, PN_WMU = 1024, PN_WLV = 1024;
constexpr int PN_TOT = PN_W1 + PN_W2 + PN_CB + PN_WMU + PN_WLV + 256 + 32 + 32 + 32;

// ---------------------------------------------------------------------------
// Prep: pack weights into MFMA B-fragment order (lane l, elem j:
// B[k=(l>>4)*8+j][n=l&15]), pad biases. cbf: k<20 -> -2*cb, k==20 -> ||cb||^2.
// ---------------------------------------------------------------------------
__global__ __launch_bounds__(256) void prep_kernel(
    const float* __restrict__ W1, const float* __restrict__ b1,
    const float* __restrict__ W2, const float* __restrict__ b2,
    const float* __restrict__ cb,
    const float* __restrict__ Wmu, const float* __restrict__ bmu,
    const float* __restrict__ Wlv, const float* __restrict__ blv,
    unsigned char* __restrict__ ws)
{
    int e = blockIdx.x * 256 + threadIdx.x;
    if (e >= PN_TOT) return;
    __bf16* w1f  = (__bf16*)(ws + WS_W1F);
    __bf16* w2f  = (__bf16*)(ws + WS_W2F);
    __bf16* cbf  = (__bf16*)(ws + WS_CBF);
    __bf16* wmuf = (__bf16*)(ws + WS_WMUF);
    __bf16* wlvf = (__bf16*)(ws + WS_WLVF);
    float* b1p  = (float*)(ws + WS_B1P);
    float* b2p  = (float*)(ws + WS_B2P);
    float* bmup = (float*)(ws + WS_BMUP);
    float* blvp = (float*)(ws + WS_BLVP);

    if (e < PN_W1) {  // [nt][kk][lane][j]
        int j = e & 7, lane = (e >> 3) & 63, kk = (e >> 9) & 3, nt = e >> 11;
        int n = nt * 16 + (lane & 15);
        int k = kk * 32 + ((lane >> 4) << 3) + j;
        w1f[e] = (__bf16)((n < DH && k < DIN) ? W1[k * DH + n] : 0.f);
        return;
    }
    e -= PN_W1;
    if (e < PN_W2) {  // [zt][kk][lane][j], K=256 over h-dim
        int j = e & 7, lane = (e >> 3) & 63, kk = (e >> 9) & 7, zt = e >> 12;
        int n = zt * 16 + (lane & 15);
        int k = kk * 32 + ((lane >> 4) << 3) + j;
        w2f[e] = (__bf16)((n < DZ && k < DH) ? W2[k * DZ + n] : 0.f);
        return;
    }
    e -= PN_W2;
    if (e < PN_CB) {  // [ct][lane][j]: k<20: -2*cb[code][k]; k==20: ||cb_code||^2
        int j = e & 7, lane = (e >> 3) & 63, ct = e >> 9;
        int code = ct * 16 + (lane & 15);
        int d = ((lane >> 4) << 3) + j;
        float v = 0.f;
        if (d < DZ) v = -2.f * cb[code * DZ + d];
        else if (d == DZ) {
            float s = 0.f;
            #pragma unroll
            for (int dd = 0; dd < DZ; ++dd) s = fmaf(cb[code * DZ + dd], cb[code * DZ + dd], s);
            v = s;
        }
        cbf[e] = (__bf16)v;
        return;
    }
    e -= PN_CB;
    if (e < PN_WMU) {
        int j = e & 7, lane = (e >> 3) & 63, zt = e >> 9;
        int n = zt * 16 + (lane & 15);
        int k = ((lane >> 4) << 3) + j;
        wmuf[e] = (__bf16)((n < DZ && k < DZ) ? Wmu[k * DZ + n] : 0.f);
        return;
    }
    e -= PN_WMU;
    if (e < PN_WLV) {
        int j = e & 7, lane = (e >> 3) & 63, zt = e >> 9;
        int n = zt * 16 + (lane & 15);
        int k = ((lane >> 4) << 3) + j;
        wlvf[e] = (__bf16)((n < DZ && k < DZ) ? Wlv[k * DZ + n] : 0.f);
        return;
    }
    e -= PN_WLV;
    if (e < 256) { b1p[e] = (e < DH) ? b1[e] : 0.f; return; }
    e -= 256;
    if (e < 32) { b2p[e] = (e < DZ) ? b2[e] : 0.f; return; }
    e -= 32;
    if (e < 32) { bmup[e] = (e < DZ) ? bmu[e] : 0.f; return; }
    e -= 32;
    blvp[e - 32] = (e - 32 < DZ) ? blv[e - 32] : 0.f;
}

// ---------------------------------------------------------------------------
// Fused main: 128 rows/block, 4 waves, 32 rows/wave (2 M-tiles).
// LDS = exactly 32 KB (one region, phase-aliased):
//   phase 1: hT [128 rows][256 B]  (wave-private rows; bf16 swizzled)
//   phase 2: zT aliases hT rows    (wave-private; 1.0 at k=20 for cbn2 fold)
//   phase 3: mu/lv f32 staging (20 KB) -> coalesced float2 stores
//   phase 4: zq/ze f32 staging (20 KB) + loss red at +24576
// ---------------------------------------------------------------------------
__global__ __launch_bounds__(256, 4) void fused_main(
    const float* __restrict__ c, const float* __restrict__ cb,
    const unsigned char* __restrict__ ws, float* __restrict__ out,
    float* __restrict__ partials)
{
    __shared__ __align__(16) unsigned char region[32768];

    const __bf16* w1f  = (const __bf16*)(ws + WS_W1F);
    const __bf16* w2f  = (const __bf16*)(ws + WS_W2F);
    const __bf16* cbf  = (const __bf16*)(ws + WS_CBF);
    const __bf16* wmuf = (const __bf16*)(ws + WS_WMUF);
    const __bf16* wlvf = (const __bf16*)(ws + WS_WLVF);
    const float* b1p  = (const float*)(ws + WS_B1P);
    const float* b2p  = (const float*)(ws + WS_B2P);
    const float* bmup = (const float*)(ws + WS_BMUP);
    const float* blvp = (const float*)(ws + WS_BLVP);

    const int tid = threadIdx.x;
    const int l   = tid & 63;
    const int wid = __builtin_amdgcn_readfirstlane(tid >> 6);
    const int g   = l >> 4;
    const int li  = l & 15;
    const int rowB = blockIdx.x * 128;
    const int row0 = rowB + wid * 32;

    // ---- A-fragments of c (K=128 padded), held in regs for whole GEMM1 ----
    bf16x8 af[2][4];
    #pragma unroll
    for (int mt = 0; mt < 2; ++mt) {
        const float* crow = c + (size_t)(row0 + mt * 16 + li) * DIN;
        #pragma unroll
        for (int kk = 0; kk < 4; ++kk) {
            int kb = kk * 32 + g * 8;
            float4 v0 = make_float4(0.f, 0.f, 0.f, 0.f);
            float4 v1 = make_float4(0.f, 0.f, 0.f, 0.f);
            if (kb <= 96)     v0 = *(const float4*)(crow + kb);
            if (kb + 4 <= 96) v1 = *(const float4*)(crow + kb + 4);
            bf16x8 a;
            a[0] = (__bf16)v0.x; a[1] = (__bf16)v0.y; a[2] = (__bf16)v0.z; a[3] = (__bf16)v0.w;
            a[4] = (__bf16)v1.x; a[5] = (__bf16)v1.y; a[6] = (__bf16)v1.z; a[7] = (__bf16)v1.w;
            af[mt][kk] = a;
        }
    }

    // GEMM2 accumulators (init with b2 bias; col li / 16+li)
    f32x4 z00, z01, z10, z11;
    {
        float bz0 = b2p[li], bz1 = b2p[16 + li];
        z00 = f32x4{bz0, bz0, bz0, bz0}; z01 = f32x4{bz1, bz1, bz1, bz1};
        z10 = z00; z11 = z01;
    }

    unsigned char* hT = region;   // [128][256B], wave-private rows

    // ---- two half-tiles of the hidden dim ----
    #pragma unroll
    for (int hf = 0; hf < 2; ++hf) {
        #pragma unroll
        for (int t = 0; t < 8; ++t) {
            const int nt = hf * 8 + t;
            float bias = b1p[nt * 16 + li];
            f32x4 acc0 = f32x4{bias, bias, bias, bias};
            f32x4 acc1 = acc0;
            #pragma unroll
            for (int kk = 0; kk < 4; ++kk) {
                bf16x8 bw = *(const bf16x8*)(w1f + ((nt * 4 + kk) * 512 + l * 8));
                acc0 = __builtin_amdgcn_mfma_f32_16x16x32_bf16(af[0][kk], bw, acc0, 0, 0, 0);
                acc1 = __builtin_amdgcn_mfma_f32_16x16x32_bf16(af[1][kk], bw, acc1, 0, 0, 0);
            }
            // ELU + bf16 -> hT (swizzled)
            #pragma unroll
            for (int mt = 0; mt < 2; ++mt) {
                f32x4 a = mt ? acc1 : acc0;
                #pragma unroll
                for (int r = 0; r < 4; ++r) {
                    float h = a[r];
                    h = h > 0.f ? h : (__expf(h) - 1.f);
                    int lrow = wid * 32 + mt * 16 + g * 4 + r;
                    int cbyte = ((t * 16 + li) << 1) ^ ((lrow & 7) << 4);
                    *(__bf16*)(hT + lrow * 256 + cbyte) = (__bf16)h;
                }
            }
        }
        // GEMM2 partial: K-slice [hf*128, hf*128+128)  (wave-private rows)
        #pragma unroll
        for (int kk = 0; kk < 4; ++kk) {
            const int kk2 = hf * 4 + kk;
            int lrow0 = wid * 32 + li;
            int lrow1 = lrow0 + 16;
            int cb0 = (kk * 64 + g * 16) ^ ((lrow0 & 7) << 4);
            int cb1 = (kk * 64 + g * 16) ^ ((lrow1 & 7) << 4);
            bf16x8 a20 = *(const bf16x8*)(hT + lrow0 * 256 + cb0);
            bf16x8 a21 = *(const bf16x8*)(hT + lrow1 * 256 + cb1);
            bf16x8 w20 = *(const bf16x8*)(w2f + ((0 * 8 + kk2) * 512 + l * 8));
            bf16x8 w21 = *(const bf16x8*)(w2f + ((1 * 8 + kk2) * 512 + l * 8));
            z00 = __builtin_amdgcn_mfma_f32_16x16x32_bf16(a20, w20, z00, 0, 0, 0);
            z01 = __builtin_amdgcn_mfma_f32_16x16x32_bf16(a20, w21, z01, 0, 0, 0);
            z10 = __builtin_amdgcn_mfma_f32_16x16x32_bf16(a21, w20, z10, 0, 0, 0);
            z11 = __builtin_amdgcn_mfma_f32_16x16x32_bf16(a21, w21, z11, 0, 0, 0);
        }
    }

    // ---- zT (aliases own wave's hT rows): bf16 z + 1.0 at col 20 ----
    #pragma unroll
    for (int mt = 0; mt < 2; ++mt) {
        f32x4 a0 = mt ? z10 : z00;
        f32x4 a1 = mt ? z11 : z01;
        #pragma unroll
        for (int r = 0; r < 4; ++r) {
            int lrow = wid * 32 + mt * 16 + g * 4 + r;
            int swz = (lrow & 7) << 4;
            *(__bf16*)(region + lrow * 256 + ((li * 2) ^ swz)) = (__bf16)a0[r];
            __bf16 v1 = (li < 4) ? (__bf16)a1[r] : ((li == 4) ? (__bf16)1.0f : (__bf16)0.f);
            *(__bf16*)(region + lrow * 256 + (((16 + li) * 2) ^ swz)) = v1;
        }
    }

    // ---- VQ A-fragments (z rows, K=32; includes 1.0 slot at k=20) ----
    bf16x8 za0, za1;
    {
        int lrow0 = wid * 32 + li, lrow1 = lrow0 + 16;
        za0 = *(const bf16x8*)(region + lrow0 * 256 + ((g * 16) ^ ((lrow0 & 7) << 4)));
        za1 = *(const bf16x8*)(region + lrow1 * 256 + ((g * 16) ^ ((lrow1 & 7) << 4)));
    }
    __syncthreads();   // everyone done with hT/zT; region free for staging

    // ---- VQ: 32 code-tiles, running argmin (strict <, ascending idx) ----
    float bs0[4], bs1[4]; int bi0[4], bi1[4];
    #pragma unroll
    for (int r = 0; r < 4; ++r) { bs0[r] = 3.4e38f; bs1[r] = 3.4e38f; bi0[r] = 0; bi1[r] = 0; }
    const f32x4 zero4 = f32x4{0.f, 0.f, 0.f, 0.f};
    #pragma unroll 4
    for (int ct = 0; ct < 32; ++ct) {
        bf16x8 cf = *(const bf16x8*)(cbf + (ct * 512 + l * 8));
        f32x4 s0 = __builtin_amdgcn_mfma_f32_16x16x32_bf16(za0, cf, zero4, 0, 0, 0);
        f32x4 s1 = __builtin_amdgcn_mfma_f32_16x16x32_bf16(za1, cf, zero4, 0, 0, 0);
        int idx = ct * 16 + li;
        #pragma unroll
        for (int r = 0; r < 4; ++r) {
            if (s0[r] < bs0[r]) { bs0[r] = s0[r]; bi0[r] = idx; }
            if (s1[r] < bs1[r]) { bs1[r] = s1[r]; bi1[r] = idx; }
        }
    }
    #pragma unroll
    for (int m = 1; m < 16; m <<= 1) {
        #pragma unroll
        for (int r = 0; r < 4; ++r) {
            float os = __shfl_xor(bs0[r], m, 64); int oi = __shfl_xor(bi0[r], m, 64);
            if (os < bs0[r] || (os == bs0[r] && oi < bi0[r])) { bs0[r] = os; bi0[r] = oi; }
            os = __shfl_xor(bs1[r], m, 64); oi = __shfl_xor(bi1[r], m, 64);
            if (os < bs1[r] || (os == bs1[r] && oi < bi1[r])) { bs1[r] = os; bi1[r] = oi; }
        }
    }

    const size_t SEC = (size_t)BN * DZ;
    const size_t obase = (size_t)rowB * DZ;
    float* o_mu = out + obase;
    float* o_lv = out + SEC + obase;
    float* o_zq = out + 2 * SEC + obase;
    float* o_ze = out + 3 * SEC + obase;

    float* muS = (float*)region;            // 2560 f32
    float* lvS = (float*)region + 2560;

    // ---- heads: mu, logvar (A = z frags; k=20 slot * 0-weight = harmless) ----
    {
        float bm0 = bmup[li], bm1 = bmup[16 + li];
        float bv0 = blvp[li], bv1 = blvp[16 + li];
        bf16x8 wm0 = *(const bf16x8*)(wmuf + (0 * 512 + l * 8));
        bf16x8 wm1 = *(const bf16x8*)(wmuf + (1 * 512 + l * 8));
        bf16x8 wl0 = *(const bf16x8*)(wlvf + (0 * 512 + l * 8));
        bf16x8 wl1 = *(const bf16x8*)(wlvf + (1 * 512 + l * 8));
        #pragma unroll
        for (int mt = 0; mt < 2; ++mt) {
            bf16x8 za = mt ? za1 : za0;
            f32x4 m0 = f32x4{bm0, bm0, bm0, bm0};
            f32x4 m1 = f32x4{bm1, bm1, bm1, bm1};
            f32x4 v0 = f32x4{bv0, bv0, bv0, bv0};
            f32x4 v1 = f32x4{bv1, bv1, bv1, bv1};
            m0 = __builtin_amdgcn_mfma_f32_16x16x32_bf16(za, wm0, m0, 0, 0, 0);
            m1 = __builtin_amdgcn_mfma_f32_16x16x32_bf16(za, wm1, m1, 0, 0, 0);
            v0 = __builtin_amdgcn_mfma_f32_16x16x32_bf16(za, wl0, v0, 0, 0, 0);
            v1 = __builtin_amdgcn_mfma_f32_16x16x32_bf16(za, wl1, v1, 0, 0, 0);
            #pragma unroll
            for (int r = 0; r < 4; ++r) {
                int lrow = wid * 32 + mt * 16 + g * 4 + r;
                muS[lrow * DZ + li] = m0[r];
                lvS[lrow * DZ + li] = v0[r];
                if (li < 4) {
                    muS[lrow * DZ + 16 + li] = m1[r];
                    lvS[lrow * DZ + 16 + li] = v1[r];
                }
            }
        }
    }
    __syncthreads();
    // coalesced copy-out: 2560 f32 per array, float2 x5 per thread
    #pragma unroll
    for (int i = 0; i < 5; ++i) {
        int w = tid * 2 + i * 512;
        *(float2*)(o_mu + w) = *(const float2*)(muS + w);
        *(float2*)(o_lv + w) = *(const float2*)(lvS + w);
    }
    __syncthreads();

    // ---- round B: zq gather + loss + ze staging ----
    float* zqS  = (float*)region;
    float* zeS  = (float*)region + 2560;
    float* redf = (float*)(region + 24576);   // disjoint from zqS/zeS

    float lsum = 0.f;
    #pragma unroll
    for (int mt = 0; mt < 2; ++mt) {
        f32x4 a0 = mt ? z10 : z00;
        f32x4 a1 = mt ? z11 : z01;
        #pragma unroll
        for (int r = 0; r < 4; ++r) {
            int lrow = wid * 32 + mt * 16 + g * 4 + r;
            int idx = mt ? bi1[r] : bi0[r];
            float qv = cb[idx * DZ + li];
            zqS[lrow * DZ + li] = qv;
            zeS[lrow * DZ + li] = a0[r];
            float d0 = qv - a0[r];
            lsum = fmaf(d0, d0, lsum);
            if (li < 4) {
                float qv2 = cb[idx * DZ + 16 + li];
                zqS[lrow * DZ + 16 + li] = qv2;
                zeS[lrow * DZ + 16 + li] = a1[r];
                float d1 = qv2 - a1[r];
                lsum = fmaf(d1, d1, lsum);
            }
        }
    }
    #pragma unroll
    for (int off = 32; off > 0; off >>= 1) lsum += __shfl_down(lsum, off, 64);
    if (l == 0) redf[wid] = lsum;
    __syncthreads();
    #pragma unroll
    for (int i = 0; i < 5; ++i) {
        int w = tid * 2 + i * 512;
        *(float2*)(o_zq + w) = *(const float2*)(zqS + w);
        *(float2*)(o_ze + w) = *(const float2*)(zeS + w);
    }
    if (tid == 0)
        partials[blockIdx.x] = (redf[0] + redf[1]) + (redf[2] + redf[3]);
}

// ---------------------------------------------------------------------------
// Final reduction: 2048 partials -> two scalar losses (deterministic tree)
// ---------------------------------------------------------------------------
__global__ __launch_bounds__(256) void loss_reduce(const float* __restrict__ partials,
                                                   float* __restrict__ out_scalars) {
    int t = threadIdx.x;
    float s = 0.f;
    #pragma unroll
    for (int i = 0; i < 8; ++i) s += partials[t + 256 * i];
    #pragma unroll
    for (int off = 32; off > 0; off >>= 1) s += __shfl_down(s, off, 64);
    __shared__ float wsum[4];
    if ((t & 63) == 0) wsum[t >> 6] = s;
    __syncthreads();
    if (t == 0) {
        float total = (wsum[0] + wsum[1]) + (wsum[2] + wsum[3]);
        float ql = total / (float)((size_t)BN * DZ);
        out_scalars[0] = ql;          // quantization_loss
        out_scalars[1] = 0.25f * ql;  // commitment_loss
    }
}

// ---------------------------------------------------------------------------
extern "C" void kernel_launch(void* const* d_in, const int* in_sizes, int n_in,
                              void* d_out, int out_size, void* d_ws, size_t ws_size,
                              hipStream_t stream) {
    const float* c   = (const float*)d_in[0];
    const float* W1  = (const float*)d_in[1];
    const float* b1  = (const float*)d_in[2];
    const float* W2  = (const float*)d_in[3];
    const float* b2  = (const float*)d_in[4];
    const float* cb  = (const float*)d_in[5];
    const float* Wmu = (const float*)d_in[6];
    const float* bmu = (const float*)d_in[7];
    const float* Wlv = (const float*)d_in[8];
    const float* blv = (const float*)d_in[9];
    float* out = (float*)d_out;
    unsigned char* ws = (unsigned char*)d_ws;
    float* partials = (float*)(ws + WS_PART);

    prep_kernel<<<(PN_TOT + 255) / 256, 256, 0, stream>>>(
        W1, b1, W2, b2, cb, Wmu, bmu, Wlv, blv, ws);
    fused_main<<<BN / 128, 256, 0, stream>>>(c, cb, ws, out, partials);
    loss_reduce<<<1, 256, 0, stream>>>(partials, out + 4 * (size_t)BN * DZ);
}

// Round 5
// 107.709 us; speedup vs baseline: 1.1204x; 1.1204x over previous
//
#include <hip/hip_runtime.h>

typedef __bf16 bf16x8 __attribute__((ext_vector_type(8)));
typedef float  f32x4  __attribute__((ext_vector_type(4)));
typedef float  f32x2  __attribute__((ext_vector_type(2)));

constexpr int BN  = 262144;
constexpr int DIN = 100;
constexpr int DH  = 200;
constexpr int DZ  = 20;
constexpr int KCB = 512;

// ws byte offsets (all 16B-aligned)
constexpr size_t WS_W1F  = 0;        // [16 nt][4 kk][512] bf16 = 65536 B
constexpr size_t WS_W2F  = 65536;    // [2 zt][8 kk][512] bf16 = 16384 B
constexpr size_t WS_CBF  = 81920;    // [32 ct][512] bf16 = 32768 B (k=20 slot holds ||cb||^2)
constexpr size_t WS_WMUF = 114688;   // [2 zt][512] bf16 = 2048 B
constexpr size_t WS_WLVF = 116736;   // 2048 B
constexpr size_t WS_B1P  = 118784;   // 256 f32
constexpr size_t WS_B2P  = 119808;   // 32 f32
constexpr size_t WS_BMUP = 119936;   // 32 f32
constexpr size_t WS_BLVP = 120064;   // 32 f32
constexpr size_t WS_PART = 120192;   // 8192 f32 (per-WAVE loss partials)

// prep element counts
constexpr int PN_W1 = 32768, PN_W2 = 8192, PN_CB = 16384, PN_WMU = 1024, PN_WLV = 1024;
constexpr int PN_TOT = PN_W1 + PN_W2 + PN_CB + PN_WMU + PN_WLV + 256 + 32 + 32 + 32;

// ---------------------------------------------------------------------------
// Prep: pack weights into MFMA B-fragment order (lane l, elem j:
// B[k=(l>>4)*8+j][n=l&15]), pad biases. cbf: k<20 -> -2*cb, k==20 -> ||cb||^2.
// ---------------------------------------------------------------------------
__global__ __launch_bounds__(256) void prep_kernel(
    const float* __restrict__ W1, const float* __restrict__ b1,
    const float* __restrict__ W2, const float* __restrict__ b2,
    const float* __restrict__ cb,
    const float* __restrict__ Wmu, const float* __restrict__ bmu,
    const float* __restrict__ Wlv, const float* __restrict__ blv,
    unsigned char* __restrict__ ws)
{
    int e = blockIdx.x * 256 + threadIdx.x;
    if (e >= PN_TOT) return;
    __bf16* w1f  = (__bf16*)(ws + WS_W1F);
    __bf16* w2f  = (__bf16*)(ws + WS_W2F);
    __bf16* cbf  = (__bf16*)(ws + WS_CBF);
    __bf16* wmuf = (__bf16*)(ws + WS_WMUF);
    __bf16* wlvf = (__bf16*)(ws + WS_WLVF);
    float* b1p  = (float*)(ws + WS_B1P);
    float* b2p  = (float*)(ws + WS_B2P);
    float* bmup = (float*)(ws + WS_BMUP);
    float* blvp = (float*)(ws + WS_BLVP);

    if (e < PN_W1) {  // [nt][kk][lane][j]
        int j = e & 7, lane = (e >> 3) & 63, kk = (e >> 9) & 3, nt = e >> 11;
        int n = nt * 16 + (lane & 15);
        int k = kk * 32 + ((lane >> 4) << 3) + j;
        w1f[e] = (__bf16)((n < DH && k < DIN) ? W1[k * DH + n] : 0.f);
        return;
    }
    e -= PN_W1;
    if (e < PN_W2) {  // [zt][kk][lane][j], K=256 over h-dim
        int j = e & 7, lane = (e >> 3) & 63, kk = (e >> 9) & 7, zt = e >> 12;
        int n = zt * 16 + (lane & 15);
        int k = kk * 32 + ((lane >> 4) << 3) + j;
        w2f[e] = (__bf16)((n < DZ && k < DH) ? W2[k * DZ + n] : 0.f);
        return;
    }
    e -= PN_W2;
    if (e < PN_CB) {  // [ct][lane][j]: k<20: -2*cb[code][k]; k==20: ||cb_code||^2
        int j = e & 7, lane = (e >> 3) & 63, ct = e >> 9;
        int code = ct * 16 + (lane & 15);
        int d = ((lane >> 4) << 3) + j;
        float v = 0.f;
        if (d < DZ) v = -2.f * cb[code * DZ + d];
        else if (d == DZ) {
            float s = 0.f;
            #pragma unroll
            for (int dd = 0; dd < DZ; ++dd) s = fmaf(cb[code * DZ + dd], cb[code * DZ + dd], s);
            v = s;
        }
        cbf[e] = (__bf16)v;
        return;
    }
    e -= PN_CB;
    if (e < PN_WMU) {
        int j = e & 7, lane = (e >> 3) & 63, zt = e >> 9;
        int n = zt * 16 + (lane & 15);
        int k = ((lane >> 4) << 3) + j;
        wmuf[e] = (__bf16)((n < DZ && k < DZ) ? Wmu[k * DZ + n] : 0.f);
        return;
    }
    e -= PN_WMU;
    if (e < PN_WLV) {
        int j = e & 7, lane = (e >> 3) & 63, zt = e >> 9;
        int n = zt * 16 + (lane & 15);
        int k = ((lane >> 4) << 3) + j;
        wlvf[e] = (__bf16)((n < DZ && k < DZ) ? Wlv[k * DZ + n] : 0.f);
        return;
    }
    e -= PN_WLV;
    if (e < 256) { b1p[e] = (e < DH) ? b1[e] : 0.f; return; }
    e -= 256;
    if (e < 32) { b2p[e] = (e < DZ) ? b2[e] : 0.f; return; }
    e -= 32;
    if (e < 32) { bmup[e] = (e < DZ) ? bmu[e] : 0.f; return; }
    e -= 32;
    blvp[e - 32] = (e - 32 < DZ) ? blv[e - 32] : 0.f;
}

// ---------------------------------------------------------------------------
// Fused main: 128 rows/block, 4 waves, 32 rows/wave (2 M-tiles).
// LDS = exactly 40960 B (one region, phase-aliased; 4 blocks/CU):
//   phase 1: hT/zT [128 rows][256 B] (wave-private rows; bf16 swizzled)
//   phase 2: mu/lv/zq/ze f32 staging (4 x 10240 B) -> nontemporal float2 out
// Barriers: 2 (end of frag reads; end of staging writes).
// ---------------------------------------------------------------------------
__global__ __launch_bounds__(256) void fused_main(
    const float* __restrict__ c, const float* __restrict__ cb,
    const unsigned char* __restrict__ ws, float* __restrict__ out,
    float* __restrict__ partials)
{
    __shared__ __align__(16) unsigned char region[40960];

    const __bf16* w1f  = (const __bf16*)(ws + WS_W1F);
    const __bf16* w2f  = (const __bf16*)(ws + WS_W2F);
    const __bf16* cbf  = (const __bf16*)(ws + WS_CBF);
    const __bf16* wmuf = (const __bf16*)(ws + WS_WMUF);
    const __bf16* wlvf = (const __bf16*)(ws + WS_WLVF);
    const float* b1p  = (const float*)(ws + WS_B1P);
    const float* b2p  = (const float*)(ws + WS_B2P);
    const float* bmup = (const float*)(ws + WS_BMUP);
    const float* blvp = (const float*)(ws + WS_BLVP);

    const int tid = threadIdx.x;
    const int l   = tid & 63;
    const int wid = __builtin_amdgcn_readfirstlane(tid >> 6);
    const int g   = l >> 4;
    const int li  = l & 15;
    const int rowB = blockIdx.x * 128;
    const int row0 = rowB + wid * 32;

    // ---- A-fragments of c (K=128 padded), held in regs for whole GEMM1 ----
    bf16x8 af[2][4];
    #pragma unroll
    for (int mt = 0; mt < 2; ++mt) {
        const float* crow = c + (size_t)(row0 + mt * 16 + li) * DIN;
        #pragma unroll
        for (int kk = 0; kk < 4; ++kk) {
            int kb = kk * 32 + g * 8;
            float4 v0 = make_float4(0.f, 0.f, 0.f, 0.f);
            float4 v1 = make_float4(0.f, 0.f, 0.f, 0.f);
            if (kb <= 96)     v0 = *(const float4*)(crow + kb);
            if (kb + 4 <= 96) v1 = *(const float4*)(crow + kb + 4);
            bf16x8 a;
            a[0] = (__bf16)v0.x; a[1] = (__bf16)v0.y; a[2] = (__bf16)v0.z; a[3] = (__bf16)v0.w;
            a[4] = (__bf16)v1.x; a[5] = (__bf16)v1.y; a[6] = (__bf16)v1.z; a[7] = (__bf16)v1.w;
            af[mt][kk] = a;
        }
    }

    // GEMM2 accumulators (init with b2 bias; col li / 16+li)
    f32x4 z00, z01, z10, z11;
    {
        float bz0 = b2p[li], bz1 = b2p[16 + li];
        z00 = f32x4{bz0, bz0, bz0, bz0}; z01 = f32x4{bz1, bz1, bz1, bz1};
        z10 = z00; z11 = z01;
    }

    unsigned char* hT = region;   // [128][256B], wave-private rows

    // ---- two half-tiles of the hidden dim ----
    #pragma unroll
    for (int hf = 0; hf < 2; ++hf) {
        #pragma unroll
        for (int t = 0; t < 8; ++t) {
            const int nt = hf * 8 + t;
            float bias = b1p[nt * 16 + li];
            f32x4 acc0 = f32x4{bias, bias, bias, bias};
            f32x4 acc1 = acc0;
            #pragma unroll
            for (int kk = 0; kk < 4; ++kk) {
                bf16x8 bw = *(const bf16x8*)(w1f + ((nt * 4 + kk) * 512 + l * 8));
                acc0 = __builtin_amdgcn_mfma_f32_16x16x32_bf16(af[0][kk], bw, acc0, 0, 0, 0);
                acc1 = __builtin_amdgcn_mfma_f32_16x16x32_bf16(af[1][kk], bw, acc1, 0, 0, 0);
            }
            // ELU + bf16 -> hT (swizzled)
            #pragma unroll
            for (int mt = 0; mt < 2; ++mt) {
                f32x4 a = mt ? acc1 : acc0;
                #pragma unroll
                for (int r = 0; r < 4; ++r) {
                    float h = a[r];
                    h = h > 0.f ? h : (__expf(h) - 1.f);
                    int lrow = wid * 32 + mt * 16 + g * 4 + r;
                    int cbyte = ((t * 16 + li) << 1) ^ ((lrow & 7) << 4);
                    *(__bf16*)(hT + lrow * 256 + cbyte) = (__bf16)h;
                }
            }
        }
        // GEMM2 partial: K-slice [hf*128, hf*128+128)  (wave-private rows)
        #pragma unroll
        for (int kk = 0; kk < 4; ++kk) {
            const int kk2 = hf * 4 + kk;
            int lrow0 = wid * 32 + li;
            int lrow1 = lrow0 + 16;
            int cb0 = (kk * 64 + g * 16) ^ ((lrow0 & 7) << 4);
            int cb1 = (kk * 64 + g * 16) ^ ((lrow1 & 7) << 4);
            bf16x8 a20 = *(const bf16x8*)(hT + lrow0 * 256 + cb0);
            bf16x8 a21 = *(const bf16x8*)(hT + lrow1 * 256 + cb1);
            bf16x8 w20 = *(const bf16x8*)(w2f + ((0 * 8 + kk2) * 512 + l * 8));
            bf16x8 w21 = *(const bf16x8*)(w2f + ((1 * 8 + kk2) * 512 + l * 8));
            z00 = __builtin_amdgcn_mfma_f32_16x16x32_bf16(a20, w20, z00, 0, 0, 0);
            z01 = __builtin_amdgcn_mfma_f32_16x16x32_bf16(a20, w21, z01, 0, 0, 0);
            z10 = __builtin_amdgcn_mfma_f32_16x16x32_bf16(a21, w20, z10, 0, 0, 0);
            z11 = __builtin_amdgcn_mfma_f32_16x16x32_bf16(a21, w21, z11, 0, 0, 0);
        }
    }

    // ---- zT (aliases own wave's hT rows): bf16 z + 1.0 at col 20 ----
    #pragma unroll
    for (int mt = 0; mt < 2; ++mt) {
        f32x4 a0 = mt ? z10 : z00;
        f32x4 a1 = mt ? z11 : z01;
        #pragma unroll
        for (int r = 0; r < 4; ++r) {
            int lrow = wid * 32 + mt * 16 + g * 4 + r;
            int swz = (lrow & 7) << 4;
            *(__bf16*)(region + lrow * 256 + ((li * 2) ^ swz)) = (__bf16)a0[r];
            __bf16 v1 = (li < 4) ? (__bf16)a1[r] : ((li == 4) ? (__bf16)1.0f : (__bf16)0.f);
            *(__bf16*)(region + lrow * 256 + (((16 + li) * 2) ^ swz)) = v1;
        }
    }

    // ---- VQ A-fragments (z rows, K=32; includes 1.0 slot at k=20) ----
    bf16x8 za0, za1;
    {
        int lrow0 = wid * 32 + li, lrow1 = lrow0 + 16;
        za0 = *(const bf16x8*)(region + lrow0 * 256 + ((g * 16) ^ ((lrow0 & 7) << 4)));
        za1 = *(const bf16x8*)(region + lrow1 * 256 + ((g * 16) ^ ((lrow1 & 7) << 4)));
    }
    __syncthreads();   // all waves done with hT/zT; region free for staging

    // ---- VQ: 32 code-tiles, running argmin (strict <, ascending idx) ----
    float bs0[4], bs1[4]; int bi0[4], bi1[4];
    #pragma unroll
    for (int r = 0; r < 4; ++r) { bs0[r] = 3.4e38f; bs1[r] = 3.4e38f; bi0[r] = 0; bi1[r] = 0; }
    const f32x4 zero4 = f32x4{0.f, 0.f, 0.f, 0.f};
    #pragma unroll 4
    for (int ct = 0; ct < 32; ++ct) {
        bf16x8 cf = *(const bf16x8*)(cbf + (ct * 512 + l * 8));
        f32x4 s0 = __builtin_amdgcn_mfma_f32_16x16x32_bf16(za0, cf, zero4, 0, 0, 0);
        f32x4 s1 = __builtin_amdgcn_mfma_f32_16x16x32_bf16(za1, cf, zero4, 0, 0, 0);
        int idx = ct * 16 + li;
        #pragma unroll
        for (int r = 0; r < 4; ++r) {
            if (s0[r] < bs0[r]) { bs0[r] = s0[r]; bi0[r] = idx; }
            if (s1[r] < bs1[r]) { bs1[r] = s1[r]; bi1[r] = idx; }
        }
    }
    #pragma unroll
    for (int m = 1; m < 16; m <<= 1) {
        #pragma unroll
        for (int r = 0; r < 4; ++r) {
            float os = __shfl_xor(bs0[r], m, 64); int oi = __shfl_xor(bi0[r], m, 64);
            if (os < bs0[r] || (os == bs0[r] && oi < bi0[r])) { bs0[r] = os; bi0[r] = oi; }
            os = __shfl_xor(bs1[r], m, 64); oi = __shfl_xor(bi1[r], m, 64);
            if (os < bs1[r] || (os == bs1[r] && oi < bi1[r])) { bs1[r] = os; bi1[r] = oi; }
        }
    }

    // staging layout: muS[0..2560) lvS[2560..5120) zqS[5120..7680) zeS[7680..10240)
    float* muS = (float*)region;
    float* lvS = (float*)region + 2560;
    float* zqS = (float*)region + 5120;
    float* zeS = (float*)region + 7680;

    // ---- heads: mu, logvar (A = z frags; k=20 slot * 0-weight = harmless) ----
    {
        float bm0 = bmup[li], bm1 = bmup[16 + li];
        float bv0 = blvp[li], bv1 = blvp[16 + li];
        bf16x8 wm0 = *(const bf16x8*)(wmuf + (0 * 512 + l * 8));
        bf16x8 wm1 = *(const bf16x8*)(wmuf + (1 * 512 + l * 8));
        bf16x8 wl0 = *(const bf16x8*)(wlvf + (0 * 512 + l * 8));
        bf16x8 wl1 = *(const bf16x8*)(wlvf + (1 * 512 + l * 8));
        #pragma unroll
        for (int mt = 0; mt < 2; ++mt) {
            bf16x8 za = mt ? za1 : za0;
            f32x4 m0 = f32x4{bm0, bm0, bm0, bm0};
            f32x4 m1 = f32x4{bm1, bm1, bm1, bm1};
            f32x4 v0 = f32x4{bv0, bv0, bv0, bv0};
            f32x4 v1 = f32x4{bv1, bv1, bv1, bv1};
            m0 = __builtin_amdgcn_mfma_f32_16x16x32_bf16(za, wm0, m0, 0, 0, 0);
            m1 = __builtin_amdgcn_mfma_f32_16x16x32_bf16(za, wm1, m1, 0, 0, 0);
            v0 = __builtin_amdgcn_mfma_f32_16x16x32_bf16(za, wl0, v0, 0, 0, 0);
            v1 = __builtin_amdgcn_mfma_f32_16x16x32_bf16(za, wl1, v1, 0, 0, 0);
            #pragma unroll
            for (int r = 0; r < 4; ++r) {
                int lrow = wid * 32 + mt * 16 + g * 4 + r;
                muS[lrow * DZ + li] = m0[r];
                lvS[lrow * DZ + li] = v0[r];
                if (li < 4) {
                    muS[lrow * DZ + 16 + li] = m1[r];
                    lvS[lrow * DZ + 16 + li] = v1[r];
                }
            }
        }
    }

    // ---- zq gather + loss + ze staging ----
    float lsum = 0.f;
    #pragma unroll
    for (int mt = 0; mt < 2; ++mt) {
        f32x4 a0 = mt ? z10 : z00;
        f32x4 a1 = mt ? z11 : z01;
        #pragma unroll
        for (int r = 0; r < 4; ++r) {
            int lrow = wid * 32 + mt * 16 + g * 4 + r;
            int idx = mt ? bi1[r] : bi0[r];
            float qv = cb[idx * DZ + li];
            zqS[lrow * DZ + li] = qv;
            zeS[lrow * DZ + li] = a0[r];
            float d0 = qv - a0[r];
            lsum = fmaf(d0, d0, lsum);
            if (li < 4) {
                float qv2 = cb[idx * DZ + 16 + li];
                zqS[lrow * DZ + 16 + li] = qv2;
                zeS[lrow * DZ + 16 + li] = a1[r];
                float d1 = qv2 - a1[r];
                lsum = fmaf(d1, d1, lsum);
            }
        }
    }
    // per-wave loss partial straight to global (no LDS, no extra barrier)
    #pragma unroll
    for (int off = 32; off > 0; off >>= 1) lsum += __shfl_down(lsum, off, 64);
    if (l == 0) partials[blockIdx.x * 4 + wid] = lsum;

    __syncthreads();   // staging complete

    // ---- coalesced nontemporal copy-out: 4 x 2560 f32, float2 x5 each ----
    const size_t SEC = (size_t)BN * DZ;
    const size_t obase = (size_t)rowB * DZ;
    float* o_mu = out + obase;
    float* o_lv = out + SEC + obase;
    float* o_zq = out + 2 * SEC + obase;
    float* o_ze = out + 3 * SEC + obase;
    #pragma unroll
    for (int i = 0; i < 5; ++i) {
        int w = tid * 2 + i * 512;
        __builtin_nontemporal_store(*(const f32x2*)(muS + w), (f32x2*)(o_mu + w));
        __builtin_nontemporal_store(*(const f32x2*)(lvS + w), (f32x2*)(o_lv + w));
        __builtin_nontemporal_store(*(const f32x2*)(zqS + w), (f32x2*)(o_zq + w));
        __builtin_nontemporal_store(*(const f32x2*)(zeS + w), (f32x2*)(o_ze + w));
    }
}

// ---------------------------------------------------------------------------
// Final reduction: 8192 per-wave partials -> two scalar losses (deterministic)
// ---------------------------------------------------------------------------
__global__ __launch_bounds__(256) void loss_reduce(const float* __restrict__ partials,
                                                   float* __restrict__ out_scalars) {
    int t = threadIdx.x;
    float s = 0.f;
    #pragma unroll
    for (int i = 0; i < 32; ++i) s += partials[t + 256 * i];
    #pragma unroll
    for (int off = 32; off > 0; off >>= 1) s += __shfl_down(s, off, 64);
    __shared__ float wsum[4];
    if ((t & 63) == 0) wsum[t >> 6] = s;
    __syncthreads();
    if (t == 0) {
        float total = (wsum[0] + wsum[1]) + (wsum[2] + wsum[3]);
        float ql = total / (float)((size_t)BN * DZ);
        out_scalars[0] = ql;          // quantization_loss
        out_scalars[1] = 0.25f * ql;  // commitment_loss
    }
}

// ---------------------------------------------------------------------------
extern "C" void kernel_launch(void* const* d_in, const int* in_sizes, int n_in,
                              void* d_out, int out_size, void* d_ws, size_t ws_size,
                              hipStream_t stream) {
    const float* c   = (const float*)d_in[0];
    const float* W1  = (const float*)d_in[1];
    const float* b1  = (const float*)d_in[2];
    const float* W2  = (const float*)d_in[3];
    const float* b2  = (const float*)d_in[4];
    const float* cb  = (const float*)d_in[5];
    const float* Wmu = (const float*)d_in[6];
    const float* bmu = (const float*)d_in[7];
    const float* Wlv = (const float*)d_in[8];
    const float* blv = (const float*)d_in[9];
    float* out = (float*)d_out;
    unsigned char* ws = (unsigned char*)d_ws;
    float* partials = (float*)(ws + WS_PART);

    prep_kernel<<<(PN_TOT + 255) / 256, 256, 0, stream>>>(
        W1, b1, W2, b2, cb, Wmu, bmu, Wlv, blv, ws);
    fused_main<<<BN / 128, 256, 0, stream>>>(c, cb, ws, out, partials);
    loss_reduce<<<1, 256, 0, stream>>>(partials, out + 4 * (size_t)BN * DZ);
}